// Round 8
// baseline (803.105 us; speedup 1.0000x reference)
//
#include <hip/hip_runtime.h>
#include <hip/hip_bf16.h>
#include <math.h>

#define H 512
#define NT 6

// edge GEMM tile
#define EBM 128
#define EBN 256
#define EBK 32
// gru GEMM tile
#define GBM 128
#define GBN 64
#define GBK 32

// fixed-point scale for deterministic edge scatter (int32 atomics)
#define PSCALE 65536.0f
#define PINV   (1.0f / 65536.0f)

typedef short bf16x8 __attribute__((ext_vector_type(8)));
typedef float f32x4 __attribute__((ext_vector_type(4)));

__device__ __forceinline__ float sigmoidf_(float x) { return 1.0f / (1.0f + expf(-x)); }

__device__ __forceinline__ unsigned short f2bf(float f) {
    unsigned int u = __float_as_uint(f);
    u = (u + 0x7FFF + ((u >> 16) & 1)) >> 16;
    return (unsigned short)u;
}

// async global->LDS, 16B per lane. LDS dest must be lane-linear (wave base + lane*16);
// global src may be per-lane (gather ok) -> swizzle is done on the GLOBAL side (rule #21).
__device__ __forceinline__ void glds16(const void* g, void* l) {
    __builtin_amdgcn_global_load_lds((const __attribute__((address_space(1))) unsigned int*)g,
                                     (__attribute__((address_space(3))) unsigned int*)l,
                                     16, 0, 0);
}

// counted-vmcnt wait + raw barrier (T4) with the r4 race fix:
// drain lgkmcnt(0) BEFORE the barrier (raw s_barrier has no implicit waitcnt).
#define WAITBAR(N)                                                        \
    {                                                                     \
        asm volatile("s_waitcnt vmcnt(" #N ") lgkmcnt(0)" ::: "memory");  \
        __builtin_amdgcn_s_barrier();                                     \
        asm volatile("" ::: "memory");                                    \
    }

// col-major bijective XCD chunking (T1 + m204): each XCD gets a contiguous
// col-major chunk of tiles -> its B/weight column-slice stays L2-resident.
__device__ __forceinline__ void xcd_colmajor_map(int gx, int gy, int* rowT, int* colT) {
    const int nwg = gx * gy;
    const int bid = (int)(blockIdx.y * gridDim.x + blockIdx.x);  // hw linear (x-fastest)
    const int x = bid & 7;        // dispatch round-robins XCDs
    const int o = bid >> 3;
    const int q = nwg >> 3, rr = nwg & 7;
    const int L = (x < rr) ? x * (q + 1) + o : rr * (q + 1) + (x - rr) * q + o;
    *colT = L / gy;               // col-major decode
    *rowT = L % gy;
}

// ---------------- edge-type counting sort (block-aggregated atomics) ----------------
// meta layout (ints): [0..7]=counts, [8..14]=paddedStart (NT+1 used), [16..23]=cursor
__global__ void hist_kernel(const int* __restrict__ etype, int E, int* __restrict__ meta) {
    __shared__ int lh[NT];
    if (threadIdx.x < NT) lh[threadIdx.x] = 0;
    __syncthreads();
    int i = blockIdx.x * blockDim.x + threadIdx.x;
    if (i < E) atomicAdd(&lh[etype[i]], 1);
    __syncthreads();
    if (threadIdx.x < NT) {
        int c = lh[threadIdx.x];
        if (c) atomicAdd(&meta[threadIdx.x], c);
    }
}

__global__ void prefix_kernel(int* __restrict__ meta) {
    if (threadIdx.x == 0 && blockIdx.x == 0) {
        int acc = 0;
        for (int t = 0; t < NT; ++t) {
            meta[8 + t]  = acc;
            meta[16 + t] = acc;
            acc += ((meta[t] + EBM - 1) / EBM) * EBM;
        }
        meta[8 + NT] = acc;
    }
}

__global__ void scatter_perm_kernel(const int* __restrict__ etype, int E,
                                    int* __restrict__ meta, int* __restrict__ perm) {
    __shared__ int lcount[NT];
    __shared__ int lbase[NT];
    const int tid = threadIdx.x;
    if (tid < NT) lcount[tid] = 0;
    __syncthreads();
    int i = blockIdx.x * blockDim.x + tid;
    int t = 0, rank = 0;
    if (i < E) {
        t = etype[i];
        rank = atomicAdd(&lcount[t], 1);      // intra-block rank (LDS)
    }
    __syncthreads();
    if (tid < NT) {
        int c = lcount[tid];
        lbase[tid] = c ? atomicAdd(&meta[16 + tid], c) : 0;  // reserve block span
    }
    __syncthreads();
    if (i < E) perm[lbase[t] + rank] = i;
}

// ---------------- fp32 -> bf16 into AH[N][1024] high half (emb) ----------------
__global__ void conv_to_ah(const float* __restrict__ in, unsigned short* __restrict__ AH,
                           int n4, int half) {
    int i = blockIdx.x * blockDim.x + threadIdx.x;
    if (i < n4) {
        float4 v = ((const float4*)in)[i];
        ushort4 o;
        o.x = f2bf(v.x); o.y = f2bf(v.y); o.z = f2bf(v.z); o.w = f2bf(v.w);
        int row = i >> 7;            // 128 float4 per 512-col row
        int c4  = i & 127;
        ((ushort4*)AH)[row * 256 + half * 128 + c4] = o;   // AH row stride 1024 shorts
    }
}

// ---------------- int32 fixed-point -> bf16 into AH[N][1024] low half (proposed) ----------------
__global__ void conv_i2ah(const int* __restrict__ in, unsigned short* __restrict__ AH, int n4) {
    int i = blockIdx.x * blockDim.x + threadIdx.x;
    if (i < n4) {
        int4 v = ((const int4*)in)[i];
        ushort4 o;
        o.x = f2bf((float)v.x * PINV); o.y = f2bf((float)v.y * PINV);
        o.z = f2bf((float)v.z * PINV); o.w = f2bf((float)v.w * PINV);
        int row = i >> 7;
        int c4  = i & 127;
        ((ushort4*)AH)[row * 256 + c4] = o;                // low half
    }
}

// ---------------- GRU weights -> bf16, transposed B^T[n][k], K=1024 = [input | hidden] ----------------
__global__ void conv_gru_w_kernel(const float* __restrict__ Wir, const float* __restrict__ Wiz,
                                  const float* __restrict__ Win, const float* __restrict__ Whr,
                                  const float* __restrict__ Whz, const float* __restrict__ Whn,
                                  unsigned short* __restrict__ Brt, unsigned short* __restrict__ Bzt,
                                  unsigned short* __restrict__ Bnt) {
    int idx = blockIdx.x * blockDim.x + threadIdx.x;
    if (idx >= 512 * 1024) return;
    int n = idx >> 10;
    int k = idx & 1023;
    int kk = k & 511;
    const float* wr = (k < 512) ? Wir : Whr;
    const float* wz = (k < 512) ? Wiz : Whz;
    const float* wn = (k < 512) ? Win : Whn;
    Brt[idx] = f2bf(wr[kk * H + n]);
    Bzt[idx] = f2bf(wz[kk * H + n]);
    Bnt[idx] = f2bf(wn[kk * H + n]);
}

// W_edge (512 x 3072) -> WeT[3072][512] bf16
__global__ void conv_edge_w_kernel(const float* __restrict__ W_edge, unsigned short* __restrict__ WeT) {
    int idx = blockIdx.x * blockDim.x + threadIdx.x;
    if (idx >= 3072 * 512) return;
    int n = idx >> 9;
    int k = idx & 511;
    WeT[idx] = f2bf(W_edge[(size_t)k * (NT * H) + n]);
}

// ---------------- edge message GEMM (MFMA, 128x256, 3-buf counted-vmcnt) + int scatter-add ----------------
__global__ __launch_bounds__(256, 2)
void edge_msg_mfma(const unsigned short* __restrict__ AH,
                   const int* __restrict__ src_idx,
                   const int* __restrict__ dst_idx,
                   const float* __restrict__ b_edge,
                   const unsigned short* __restrict__ WeT,
                   const int* __restrict__ meta,
                   const int* __restrict__ perm,
                   int* __restrict__ proposed)
{
    __shared__ short As[3][EBM * EBK];   // 3 x 8KB linear
    __shared__ short Bs[3][EBN * EBK];   // 3 x 16KB -> 72KB total
    __shared__ int ls_src[EBM];
    __shared__ int ls_dst[EBM];

    int rowT, colT;
    xcd_colmajor_map(gridDim.x, gridDim.y, &rowT, &colT);
    const int rowBase = rowT * EBM;
    if (rowBase >= meta[8 + NT]) return;
    int t = 0;
    while (rowBase >= meta[8 + t + 1]) ++t;

    const int colBase = colT * EBN;
    const int tid = threadIdx.x;

    if (tid < EBM) {
        int e = perm[rowBase + tid];
        int s = 512, d = -1;                     // padded rows read row 0's emb half (discarded)
        if (e >= 0) { s = src_idx[e] * 1024 + 512; d = dst_idx[e] * H; }  // emb = AH high half
        ls_src[tid] = s;
        ls_dst[tid] = d;
    }
    __syncthreads();

    const int lane = tid & 63;
    const int wave = tid >> 6;
    const int wm = (wave >> 1) * 64;             // wave tile 64x128 of the 128x256 block
    const int wn = (wave & 1) * 128;
    const int q = lane >> 4;
    const int r = lane & 15;

    const int rA = tid >> 2;                     // 0..63: staging row within chunk
    // T2 slot swizzle: global source slot = (tid&3) ^ f(row), f(row) = (row>>1)&3
    const int gs = (((tid & 3) ^ ((rA >> 1) & 3)) * 8);   // shorts
    // read side: LDS slot holding global slot q of row (wm|wn)+i*16+r is q ^ ((r>>1)&3)
    const int qs8 = ((q ^ ((r >> 1) & 3)) * 8);           // shorts

    const size_t s0 = (size_t)ls_src[rA] + gs;
    const size_t s1 = (size_t)ls_src[64 + rA] + gs;
    const size_t bB = ((size_t)(t * H + colBase + rA)) * H + gs;   // B rows rA, +64, +128, +192

    f32x4 acc[4][8];
    #pragma unroll
    for (int i = 0; i < 4; ++i)
        #pragma unroll
        for (int j = 0; j < 8; ++j) acc[i][j] = (f32x4){0.f, 0.f, 0.f, 0.f};

// issue K-tile S's DMA into buffer B (6 loads/thread: 2 A + 4 B)
#define ESTAGE(S, B)                                                          \
    {                                                                         \
        glds16(AH + s0 + (S) * EBK, &As[B][tid * 8]);                         \
        glds16(AH + s1 + (S) * EBK, &As[B][(256 + tid) * 8]);                 \
        glds16(WeT + bB + (S) * EBK,                 &Bs[B][tid * 8]);        \
        glds16(WeT + bB + 64 * H + (S) * EBK,  &Bs[B][(256 + tid) * 8]);      \
        glds16(WeT + bB + 128 * H + (S) * EBK, &Bs[B][(512 + tid) * 8]);      \
        glds16(WeT + bB + 192 * H + (S) * EBK, &Bs[B][(768 + tid) * 8]);      \
    }

#define ECOMPUTE(B)                                                                               \
    {                                                                                             \
        bf16x8 a[4];                                                                              \
        _Pragma("unroll")                                                                         \
        for (int i = 0; i < 4; ++i)                                                               \
            a[i] = *(const bf16x8*)&As[B][(wm + i * 16 + r) * EBK + qs8];                         \
        _Pragma("unroll")                                                                         \
        for (int j = 0; j < 8; ++j) {                                                             \
            bf16x8 b = *(const bf16x8*)&Bs[B][(wn + j * 16 + r) * EBK + qs8];                     \
            _Pragma("unroll")                                                                     \
            for (int i = 0; i < 4; ++i)                                                           \
                acc[i][j] = __builtin_amdgcn_mfma_f32_16x16x32_bf16(a[i], b, acc[i][j], 0, 0, 0); \
        }                                                                                         \
    }

    ESTAGE(0, 0);
    ESTAGE(1, 1);
    // 16 K-steps, 3-buf depth-2: wait(tile S; 6 loads of S+1 stay in flight) -> stage(S+2) -> compute(S)
    for (int s = 0; s < 14; ++s) {
        WAITBAR(6);
        ESTAGE(s + 2, (s + 2) % 3);
        ECOMPUTE(s % 3);
    }
    { WAITBAR(6); ECOMPUTE(2); }         // S = 14
    { WAITBAR(0); ECOMPUTE(0); }         // S = 15
#undef ESTAGE
#undef ECOMPUTE

    int cols[8];
    float bias[8];
    #pragma unroll
    for (int j = 0; j < 8; ++j) {
        cols[j] = colBase + wn + j * 16 + r;
        bias[j] = b_edge[t * H + cols[j]];
    }
    #pragma unroll
    for (int i = 0; i < 4; ++i) {
        #pragma unroll
        for (int reg = 0; reg < 4; ++reg) {
            int row = wm + i * 16 + q * 4 + reg;
            int d = ls_dst[row];
            if (d < 0) continue;
            #pragma unroll
            for (int j = 0; j < 8; ++j)
                atomicAdd(&proposed[(size_t)d + cols[j]],
                          __float2int_rn((acc[i][j][reg] + bias[j]) * PSCALE));
        }
    }
}

// ---------------- fused GRU (MFMA, 128x64, 3-buf counted-vmcnt): A = AH[N][1024] ----------------
__global__ __launch_bounds__(256, 2)
void gru_mfma(const unsigned short* __restrict__ AH,
              const float* __restrict__ emb_f32,
              const unsigned short* __restrict__ Brt,
              const unsigned short* __restrict__ Bzt,
              const unsigned short* __restrict__ Bnt,
              const float* __restrict__ bir, const float* __restrict__ biz,
              const float* __restrict__ bin, const float* __restrict__ bhn,
              float* __restrict__ out, int N)
{
    __shared__ short As[3][GBM * GBK];    // 3 x 8KB linear
    __shared__ short Brs[3][GBN * GBK];   // 3 x 4KB
    __shared__ short Bzs[3][GBN * GBK];
    __shared__ short Bns[3][GBN * GBK];   // total 60KB -> 2 blocks/CU

    int rowT, colT;
    xcd_colmajor_map(gridDim.x, gridDim.y, &rowT, &colT);   // gru: each XCD = exactly 1 col panel
    const int rowBase = rowT * GBM;
    const int colBase = colT * GBN;

    const int tid = threadIdx.x;
    const int lane = tid & 63;
    const int wave = tid >> 6;
    const int wm = (wave >> 1) * 64;             // wave tile 64 rows x 32 cols
    const int wn = (wave & 1) * 32;
    const int q = lane >> 4;
    const int r = lane & 15;

    const int rA = tid >> 2;                     // 0..63
    const int gs = (((tid & 3) ^ ((rA >> 1) & 3)) * 8);   // T2 write-side (global slot)
    const int qs8 = ((q ^ ((r >> 1) & 3)) * 8);           // T2 read-side

    // all five staging streams are stride-1024 with compile-time S*GBK immediates
    const size_t aOff0 = (size_t)(rowBase + rA) * 1024 + gs;
    const size_t aOff1 = (size_t)(rowBase + 64 + rA) * 1024 + gs;
    const size_t bOff  = (size_t)(colBase + rA) * 1024 + gs;

    f32x4 accR[4][2], accZ[4][2], accNI[4][2], accNH[4][2];
    #pragma unroll
    for (int i = 0; i < 4; ++i)
        #pragma unroll
        for (int j = 0; j < 2; ++j) {
            accR[i][j] = (f32x4){0.f, 0.f, 0.f, 0.f};
            accZ[i][j] = accR[i][j];
            accNI[i][j] = accR[i][j];
            accNH[i][j] = accR[i][j];
        }

// stage K-step S (0..31) into buffer B (5 loads/thread, no selects)
#define GSTAGE(S, B)                                             \
    {                                                            \
        glds16(AH + aOff0 + (S) * GBK, &As[B][tid * 8]);         \
        glds16(AH + aOff1 + (S) * GBK, &As[B][(256 + tid) * 8]); \
        glds16(Brt + bOff + (S) * GBK, &Brs[B][tid * 8]);        \
        glds16(Bzt + bOff + (S) * GBK, &Bzs[B][tid * 8]);        \
        glds16(Bnt + bOff + (S) * GBK, &Bns[B][tid * 8]);        \
    }

// compute one K-step from buffer B; n-gate accumulator chosen at compile time
#define GCOMPUTE(ACCN, B)                                                                            \
    {                                                                                                \
        bf16x8 a[4];                                                                                 \
        _Pragma("unroll")                                                                            \
        for (int i = 0; i < 4; ++i)                                                                  \
            a[i] = *(const bf16x8*)&As[B][(wm + i * 16 + r) * GBK + qs8];                            \
        _Pragma("unroll")                                                                            \
        for (int j = 0; j < 2; ++j) {                                                                \
            bf16x8 br = *(const bf16x8*)&Brs[B][(wn + j * 16 + r) * GBK + qs8];                      \
            bf16x8 bz = *(const bf16x8*)&Bzs[B][(wn + j * 16 + r) * GBK + qs8];                      \
            bf16x8 bn = *(const bf16x8*)&Bns[B][(wn + j * 16 + r) * GBK + qs8];                      \
            _Pragma("unroll")                                                                        \
            for (int i = 0; i < 4; ++i) {                                                            \
                accR[i][j] = __builtin_amdgcn_mfma_f32_16x16x32_bf16(a[i], br, accR[i][j], 0, 0, 0); \
                accZ[i][j] = __builtin_amdgcn_mfma_f32_16x16x32_bf16(a[i], bz, accZ[i][j], 0, 0, 0); \
                ACCN[i][j] = __builtin_amdgcn_mfma_f32_16x16x32_bf16(a[i], bn, ACCN[i][j], 0, 0, 0); \
            }                                                                                        \
        }                                                                                            \
    }

// one steady-state step: wait(tile S, drain LDS reads) -> barrier -> stage(S+2) -> compute(S)
#define GSTEP(S, ACCN)                   \
    {                                    \
        WAITBAR(5);                      \
        GSTAGE((S) + 2, ((S) + 2) % 3);  \
        GCOMPUTE(ACCN, (S) % 3);         \
    }

    GSTAGE(0, 0);
    GSTAGE(1, 1);
    // K-steps 0..15: A = proposed half, n-gate -> accNI
    GSTEP(0,  accNI) GSTEP(1,  accNI) GSTEP(2,  accNI) GSTEP(3,  accNI)
    GSTEP(4,  accNI) GSTEP(5,  accNI) GSTEP(6,  accNI) GSTEP(7,  accNI)
    GSTEP(8,  accNI) GSTEP(9,  accNI) GSTEP(10, accNI) GSTEP(11, accNI)
    GSTEP(12, accNI) GSTEP(13, accNI) GSTEP(14, accNI) GSTEP(15, accNI)
    // K-steps 16..31: A = emb half, n-gate -> accNH
    GSTEP(16, accNH) GSTEP(17, accNH) GSTEP(18, accNH) GSTEP(19, accNH)
    GSTEP(20, accNH) GSTEP(21, accNH) GSTEP(22, accNH) GSTEP(23, accNH)
    GSTEP(24, accNH) GSTEP(25, accNH) GSTEP(26, accNH) GSTEP(27, accNH)
    GSTEP(28, accNH) GSTEP(29, accNH)
    { WAITBAR(5); GCOMPUTE(accNH, 0); }  // S = 30
    { WAITBAR(0); GCOMPUTE(accNH, 1); }  // S = 31
#undef GSTAGE
#undef GCOMPUTE
#undef GSTEP

    #pragma unroll
    for (int j = 0; j < 2; ++j) {
        const int col = colBase + wn + j * 16 + r;
        const float vbir = bir[col], vbiz = biz[col], vbin = bin[col], vbhn = bhn[col];
        #pragma unroll
        for (int i = 0; i < 4; ++i) {
            #pragma unroll
            for (int reg = 0; reg < 4; ++reg) {
                const int row = rowBase + wm + i * 16 + q * 4 + reg;
                if (row >= N) continue;
                float rg = sigmoidf_(accR[i][j][reg] + vbir);
                float zg = sigmoidf_(accZ[i][j][reg] + vbiz);
                float ng = tanhf(accNI[i][j][reg] + vbin + rg * (accNH[i][j][reg] + vbhn));
                float h = emb_f32[(size_t)row * H + col];
                out[(size_t)row * H + col] = (1.0f - zg) * ng + zg * h;
            }
        }
    }
}

extern "C" void kernel_launch(void* const* d_in, const int* in_sizes, int n_in,
                              void* d_out, int out_size, void* d_ws, size_t ws_size,
                              hipStream_t stream) {
    const float* emb     = (const float*)d_in[0];
    const int*   src_idx = (const int*)d_in[1];
    const int*   dst_idx = (const int*)d_in[2];
    const int*   etype   = (const int*)d_in[3];
    const float* W_edge  = (const float*)d_in[6];
    const float* b_edge  = (const float*)d_in[7];
    const float* Wir = (const float*)d_in[8];
    const float* Wiz = (const float*)d_in[9];
    const float* Win = (const float*)d_in[10];
    const float* bir = (const float*)d_in[11];
    const float* biz = (const float*)d_in[12];
    const float* bin = (const float*)d_in[13];
    const float* Whr = (const float*)d_in[14];
    const float* Whz = (const float*)d_in[15];
    const float* Whn = (const float*)d_in[16];
    const float* bhn = (const float*)d_in[17];

    const int E = in_sizes[1];
    const int N = in_sizes[0] / H;
    const int NH = N * H;

    char* ws = (char*)d_ws;
    int*            proposed = (int*)ws;                         ws += (size_t)NH * 4;  // fixed-point
    unsigned short* AH       = (unsigned short*)ws;              ws += (size_t)NH * 2 * 2;  // [N][1024]
    unsigned short* Brt      = (unsigned short*)ws;              ws += 512 * 1024 * 2;
    unsigned short* Bzt      = (unsigned short*)ws;              ws += 512 * 1024 * 2;
    unsigned short* Bnt      = (unsigned short*)ws;              ws += 512 * 1024 * 2;
    unsigned short* WeT      = (unsigned short*)ws;              ws += 3072 * 512 * 2;
    int*            meta     = (int*)ws;                         ws += 32 * 4;
    int*            perm     = (int*)ws;
    const int maxRowTiles = (E + EBM - 1) / EBM + NT;

    hipMemsetAsync(proposed, 0, (size_t)NH * 4, stream);
    hipMemsetAsync(meta, 0, 32 * 4, stream);
    hipMemsetAsync(perm, 0xFF, (size_t)maxRowTiles * EBM * 4, stream);

    const int n4 = NH / 4;
    conv_to_ah<<<(n4 + 255) / 256, 256, 0, stream>>>(emb, AH, n4, 1);       // emb -> high half
    conv_gru_w_kernel<<<(512 * 1024 + 255) / 256, 256, 0, stream>>>(
        Wir, Wiz, Win, Whr, Whz, Whn, Brt, Bzt, Bnt);
    conv_edge_w_kernel<<<(3072 * 512 + 255) / 256, 256, 0, stream>>>(W_edge, WeT);

    hist_kernel<<<(E + 255) / 256, 256, 0, stream>>>(etype, E, meta);
    prefix_kernel<<<1, 64, 0, stream>>>(meta);
    scatter_perm_kernel<<<(E + 255) / 256, 256, 0, stream>>>(etype, E, meta, perm);

    dim3 egrid(H / EBN, maxRowTiles);
    edge_msg_mfma<<<egrid, 256, 0, stream>>>(AH, src_idx, dst_idx, b_edge, WeT,
                                             meta, perm, proposed);

    conv_i2ah<<<(n4 + 255) / 256, 256, 0, stream>>>(proposed, AH, n4);      // proposed -> low half

    dim3 ggrid(H / GBN, (N + GBM - 1) / GBM);
    gru_mfma<<<ggrid, 256, 0, stream>>>(AH, emb, Brt, Bzt, Bnt,
                                        bir, biz, bin, bhn, (float*)d_out, N);
}

// Round 9
// 793.114 us; speedup vs baseline: 1.0126x; 1.0126x over previous
//
#include <hip/hip_runtime.h>
#include <hip/hip_bf16.h>
#include <math.h>

#define H 512
#define NT 6

// edge GEMM tile
#define EBM 128
#define EBN 256
#define EBK 32
// gru GEMM tile
#define GBM 128
#define GBN 64
#define GBK 32

// fixed-point scale for deterministic edge scatter (int32 atomics)
#define PSCALE 65536.0f
#define PINV   (1.0f / 65536.0f)

typedef short bf16x8 __attribute__((ext_vector_type(8)));
typedef float f32x4 __attribute__((ext_vector_type(4)));

__device__ __forceinline__ float sigmoidf_(float x) { return 1.0f / (1.0f + expf(-x)); }

__device__ __forceinline__ unsigned short f2bf(float f) {
    unsigned int u = __float_as_uint(f);
    u = (u + 0x7FFF + ((u >> 16) & 1)) >> 16;
    return (unsigned short)u;
}

// async global->LDS, 16B per lane. LDS dest must be lane-linear (wave base + lane*16);
// global src may be per-lane (gather ok) -> swizzle is done on the GLOBAL side (rule #21).
__device__ __forceinline__ void glds16(const void* g, void* l) {
    __builtin_amdgcn_global_load_lds((const __attribute__((address_space(1))) unsigned int*)g,
                                     (__attribute__((address_space(3))) unsigned int*)l,
                                     16, 0, 0);
}

// counted-vmcnt wait + raw barrier (T4) with the r4 race fix:
// drain lgkmcnt(0) BEFORE the barrier (raw s_barrier has no implicit waitcnt).
#define WAITBAR(N)                                                        \
    {                                                                     \
        asm volatile("s_waitcnt vmcnt(" #N ") lgkmcnt(0)" ::: "memory");  \
        __builtin_amdgcn_s_barrier();                                     \
        asm volatile("" ::: "memory");                                    \
    }

// row-band bijective XCD chunking (T1, r5-verified: FETCH 217MB vs col-major 485MB):
// each XCD gets a contiguous chunk of row-major tile order -> a row panel's col-blocks
// are adjacent in time on one XCD (A-panel L2 reuse), weight slices cycle within L2.
__device__ __forceinline__ void xcd_rowband_map(int gx, int gy, int* rowT, int* colT) {
    const int nwg = gx * gy;
    const int bid = (int)(blockIdx.y * gridDim.x + blockIdx.x);  // hw linear (x-fastest)
    const int x = bid & 7;        // dispatch round-robins XCDs
    const int o = bid >> 3;
    const int q = nwg >> 3, rr = nwg & 7;
    const int L = (x < rr) ? x * (q + 1) + o : rr * (q + 1) + (x - rr) * q + o;
    *rowT = L / gx;               // row-major decode
    *colT = L % gx;
}

// ---------------- edge-type counting sort (block-aggregated atomics) ----------------
// meta layout (ints): [0..7]=counts, [8..14]=paddedStart (NT+1 used), [16..23]=cursor
__global__ void hist_kernel(const int* __restrict__ etype, int E, int* __restrict__ meta) {
    __shared__ int lh[NT];
    if (threadIdx.x < NT) lh[threadIdx.x] = 0;
    __syncthreads();
    int i = blockIdx.x * blockDim.x + threadIdx.x;
    if (i < E) atomicAdd(&lh[etype[i]], 1);
    __syncthreads();
    if (threadIdx.x < NT) {
        int c = lh[threadIdx.x];
        if (c) atomicAdd(&meta[threadIdx.x], c);
    }
}

__global__ void prefix_kernel(int* __restrict__ meta) {
    if (threadIdx.x == 0 && blockIdx.x == 0) {
        int acc = 0;
        for (int t = 0; t < NT; ++t) {
            meta[8 + t]  = acc;
            meta[16 + t] = acc;
            acc += ((meta[t] + EBM - 1) / EBM) * EBM;
        }
        meta[8 + NT] = acc;
    }
}

__global__ void scatter_perm_kernel(const int* __restrict__ etype, int E,
                                    int* __restrict__ meta, int* __restrict__ perm) {
    __shared__ int lcount[NT];
    __shared__ int lbase[NT];
    const int tid = threadIdx.x;
    if (tid < NT) lcount[tid] = 0;
    __syncthreads();
    int i = blockIdx.x * blockDim.x + tid;
    int t = 0, rank = 0;
    if (i < E) {
        t = etype[i];
        rank = atomicAdd(&lcount[t], 1);      // intra-block rank (LDS)
    }
    __syncthreads();
    if (tid < NT) {
        int c = lcount[tid];
        lbase[tid] = c ? atomicAdd(&meta[16 + tid], c) : 0;  // reserve block span
    }
    __syncthreads();
    if (i < E) perm[lbase[t] + rank] = i;
}

// ---------------- fp32 -> bf16 into AH[N][1024] high half (emb) ----------------
__global__ void conv_to_ah(const float* __restrict__ in, unsigned short* __restrict__ AH,
                           int n4, int half) {
    int i = blockIdx.x * blockDim.x + threadIdx.x;
    if (i < n4) {
        float4 v = ((const float4*)in)[i];
        ushort4 o;
        o.x = f2bf(v.x); o.y = f2bf(v.y); o.z = f2bf(v.z); o.w = f2bf(v.w);
        int row = i >> 7;            // 128 float4 per 512-col row
        int c4  = i & 127;
        ((ushort4*)AH)[row * 256 + half * 128 + c4] = o;   // AH row stride 1024 shorts
    }
}

// ---------------- int32 fixed-point -> bf16 into AH[N][1024] low half (proposed) ----------------
__global__ void conv_i2ah(const int* __restrict__ in, unsigned short* __restrict__ AH, int n4) {
    int i = blockIdx.x * blockDim.x + threadIdx.x;
    if (i < n4) {
        int4 v = ((const int4*)in)[i];
        ushort4 o;
        o.x = f2bf((float)v.x * PINV); o.y = f2bf((float)v.y * PINV);
        o.z = f2bf((float)v.z * PINV); o.w = f2bf((float)v.w * PINV);
        int row = i >> 7;
        int c4  = i & 127;
        ((ushort4*)AH)[row * 256 + c4] = o;                // low half
    }
}

// ---------------- GRU weights -> bf16, transposed B^T[n][k], K=1024 = [input | hidden] ----------------
__global__ void conv_gru_w_kernel(const float* __restrict__ Wir, const float* __restrict__ Wiz,
                                  const float* __restrict__ Win, const float* __restrict__ Whr,
                                  const float* __restrict__ Whz, const float* __restrict__ Whn,
                                  unsigned short* __restrict__ Brt, unsigned short* __restrict__ Bzt,
                                  unsigned short* __restrict__ Bnt) {
    int idx = blockIdx.x * blockDim.x + threadIdx.x;
    if (idx >= 512 * 1024) return;
    int n = idx >> 10;
    int k = idx & 1023;
    int kk = k & 511;
    const float* wr = (k < 512) ? Wir : Whr;
    const float* wz = (k < 512) ? Wiz : Whz;
    const float* wn = (k < 512) ? Win : Whn;
    Brt[idx] = f2bf(wr[kk * H + n]);
    Bzt[idx] = f2bf(wz[kk * H + n]);
    Bnt[idx] = f2bf(wn[kk * H + n]);
}

// W_edge (512 x 3072) -> WeT[3072][512] bf16
__global__ void conv_edge_w_kernel(const float* __restrict__ W_edge, unsigned short* __restrict__ WeT) {
    int idx = blockIdx.x * blockDim.x + threadIdx.x;
    if (idx >= 3072 * 512) return;
    int n = idx >> 9;
    int k = idx & 511;
    WeT[idx] = f2bf(W_edge[(size_t)k * (NT * H) + n]);
}

// ---------------- edge message GEMM (MFMA, 128x256, 3-buf counted-vmcnt) + int scatter-add ----------------
__global__ __launch_bounds__(256, 2)
void edge_msg_mfma(const unsigned short* __restrict__ AH,
                   const int* __restrict__ src_idx,
                   const int* __restrict__ dst_idx,
                   const float* __restrict__ b_edge,
                   const unsigned short* __restrict__ WeT,
                   const int* __restrict__ meta,
                   const int* __restrict__ perm,
                   int* __restrict__ proposed)
{
    __shared__ short As[3][EBM * EBK];   // 3 x 8KB linear
    __shared__ short Bs[3][EBN * EBK];   // 3 x 16KB -> 72KB total
    __shared__ int ls_src[EBM];
    __shared__ int ls_dst[EBM];

    int rowT, colT;
    xcd_rowband_map(gridDim.x, gridDim.y, &rowT, &colT);
    const int rowBase = rowT * EBM;
    if (rowBase >= meta[8 + NT]) return;
    int t = 0;
    while (rowBase >= meta[8 + t + 1]) ++t;

    const int colBase = colT * EBN;
    const int tid = threadIdx.x;

    if (tid < EBM) {
        int e = perm[rowBase + tid];
        int s = 512, d = -1;                     // padded rows read row 0's emb half (discarded)
        if (e >= 0) { s = src_idx[e] * 1024 + 512; d = dst_idx[e] * H; }  // emb = AH high half
        ls_src[tid] = s;
        ls_dst[tid] = d;
    }
    __syncthreads();

    const int lane = tid & 63;
    const int wave = tid >> 6;
    const int wm = (wave >> 1) * 64;             // wave tile 64x128 of the 128x256 block
    const int wn = (wave & 1) * 128;
    const int q = lane >> 4;
    const int r = lane & 15;

    const int rA = tid >> 2;                     // 0..63: staging row within chunk
    // T2 slot swizzle: global source slot = (tid&3) ^ f(row), f(row) = (row>>1)&3
    const int gs = (((tid & 3) ^ ((rA >> 1) & 3)) * 8);   // shorts
    // read side: LDS slot holding global slot q of row (wm|wn)+i*16+r is q ^ ((r>>1)&3)
    const int qs8 = ((q ^ ((r >> 1) & 3)) * 8);           // shorts

    const size_t s0 = (size_t)ls_src[rA] + gs;
    const size_t s1 = (size_t)ls_src[64 + rA] + gs;
    const size_t bB = ((size_t)(t * H + colBase + rA)) * H + gs;   // B rows rA, +64, +128, +192

    f32x4 acc[4][8];
    #pragma unroll
    for (int i = 0; i < 4; ++i)
        #pragma unroll
        for (int j = 0; j < 8; ++j) acc[i][j] = (f32x4){0.f, 0.f, 0.f, 0.f};

// issue K-tile S's DMA into buffer B (6 loads/thread: 2 A + 4 B)
#define ESTAGE(S, B)                                                          \
    {                                                                         \
        glds16(AH + s0 + (S) * EBK, &As[B][tid * 8]);                         \
        glds16(AH + s1 + (S) * EBK, &As[B][(256 + tid) * 8]);                 \
        glds16(WeT + bB + (S) * EBK,                 &Bs[B][tid * 8]);        \
        glds16(WeT + bB + 64 * H + (S) * EBK,  &Bs[B][(256 + tid) * 8]);      \
        glds16(WeT + bB + 128 * H + (S) * EBK, &Bs[B][(512 + tid) * 8]);      \
        glds16(WeT + bB + 192 * H + (S) * EBK, &Bs[B][(768 + tid) * 8]);      \
    }

#define ECOMPUTE(B)                                                                               \
    {                                                                                             \
        bf16x8 a[4];                                                                              \
        _Pragma("unroll")                                                                         \
        for (int i = 0; i < 4; ++i)                                                               \
            a[i] = *(const bf16x8*)&As[B][(wm + i * 16 + r) * EBK + qs8];                         \
        _Pragma("unroll")                                                                         \
        for (int j = 0; j < 8; ++j) {                                                             \
            bf16x8 b = *(const bf16x8*)&Bs[B][(wn + j * 16 + r) * EBK + qs8];                     \
            _Pragma("unroll")                                                                     \
            for (int i = 0; i < 4; ++i)                                                           \
                acc[i][j] = __builtin_amdgcn_mfma_f32_16x16x32_bf16(a[i], b, acc[i][j], 0, 0, 0); \
        }                                                                                         \
    }

    ESTAGE(0, 0);
    ESTAGE(1, 1);
    // 16 K-steps, 3-buf depth-2: wait(tile S; 6 loads of S+1 stay in flight) -> stage(S+2) -> compute(S)
    for (int s = 0; s < 14; ++s) {
        WAITBAR(6);
        ESTAGE(s + 2, (s + 2) % 3);
        ECOMPUTE(s % 3);
    }
    { WAITBAR(6); ECOMPUTE(2); }         // S = 14
    { WAITBAR(0); ECOMPUTE(0); }         // S = 15
#undef ESTAGE
#undef ECOMPUTE

    int cols[8];
    float bias[8];
    #pragma unroll
    for (int j = 0; j < 8; ++j) {
        cols[j] = colBase + wn + j * 16 + r;
        bias[j] = b_edge[t * H + cols[j]];
    }
    #pragma unroll
    for (int i = 0; i < 4; ++i) {
        #pragma unroll
        for (int reg = 0; reg < 4; ++reg) {
            int row = wm + i * 16 + q * 4 + reg;
            int d = ls_dst[row];
            if (d < 0) continue;
            #pragma unroll
            for (int j = 0; j < 8; ++j)
                atomicAdd(&proposed[(size_t)d + cols[j]],
                          __float2int_rn((acc[i][j][reg] + bias[j]) * PSCALE));
        }
    }
}

// ---------------- fused GRU (MFMA, 128x64, 3-buf, 2-sub-phase interleave T3+T4+T5) ----------------
__global__ __launch_bounds__(256, 2)
void gru_mfma(const unsigned short* __restrict__ AH,
              const float* __restrict__ emb_f32,
              const unsigned short* __restrict__ Brt,
              const unsigned short* __restrict__ Bzt,
              const unsigned short* __restrict__ Bnt,
              const float* __restrict__ bir, const float* __restrict__ biz,
              const float* __restrict__ bin, const float* __restrict__ bhn,
              float* __restrict__ out, int N)
{
    __shared__ short As[3][GBM * GBK];    // 3 x 8KB linear
    __shared__ short Brs[3][GBN * GBK];   // 3 x 4KB
    __shared__ short Bzs[3][GBN * GBK];
    __shared__ short Bns[3][GBN * GBK];   // total 60KB -> 2 blocks/CU

    int rowT, colT;
    xcd_rowband_map(gridDim.x, gridDim.y, &rowT, &colT);  // row band/XCD: A panel L2-reused x8
    const int rowBase = rowT * GBM;
    const int colBase = colT * GBN;

    const int tid = threadIdx.x;
    const int lane = tid & 63;
    const int wave = tid >> 6;
    const int wm = (wave >> 1) * 64;             // wave tile 64 rows x 32 cols
    const int wn = (wave & 1) * 32;
    const int q = lane >> 4;
    const int r = lane & 15;

    const int rA = tid >> 2;                     // 0..63
    const int gs = (((tid & 3) ^ ((rA >> 1) & 3)) * 8);   // T2 write-side (global slot)
    const int qs8 = ((q ^ ((r >> 1) & 3)) * 8);           // T2 read-side

    // all five staging streams are stride-1024 with compile-time S*GBK immediates
    const size_t aOff0 = (size_t)(rowBase + rA) * 1024 + gs;
    const size_t aOff1 = (size_t)(rowBase + 64 + rA) * 1024 + gs;
    const size_t bOff  = (size_t)(colBase + rA) * 1024 + gs;

    f32x4 accR[4][2], accZ[4][2], accNI[4][2], accNH[4][2];
    #pragma unroll
    for (int i = 0; i < 4; ++i)
        #pragma unroll
        for (int j = 0; j < 2; ++j) {
            accR[i][j] = (f32x4){0.f, 0.f, 0.f, 0.f};
            accZ[i][j] = accR[i][j];
            accNI[i][j] = accR[i][j];
            accNH[i][j] = accR[i][j];
        }

// stage K-step S into buffer B (prologue only; steady-state staging is inside GSTEP8)
#define GSTAGE(S, B)                                             \
    {                                                            \
        glds16(AH + aOff0 + (S) * GBK, &As[B][tid * 8]);         \
        glds16(AH + aOff1 + (S) * GBK, &As[B][(256 + tid) * 8]); \
        glds16(Brt + bOff + (S) * GBK, &Brs[B][tid * 8]);        \
        glds16(Bzt + bOff + (S) * GBK, &Bzs[B][tid * 8]);        \
        glds16(Bnt + bOff + (S) * GBK, &Bns[B][tid * 8]);        \
    }

// One K-step as two fine-interleaved sub-phases (T3), each: {ds_read frags || issue DMA
// -> barrier -> lgkmcnt(0)+sched_barrier -> setprio(1) 12xMFMA setprio(0) -> barrier}.
// Counted vmcnt stays at the step-start WAITBAR (T4). Hazard ledger:
//  - stage target buf (S+2)%3 != read buf S%3 (3-buf rotation).
//  - every ds_read of buf X drains (lgkmcnt0) before a barrier that precedes the DMA
//    overwriting X (P2 reads drain before next step's WAITBAR barrier; DMA of buf
//    (S+3)%3 == S%3 issues after it).  [r4 race class covered]
#define GSTEP8(S, ACCN, DOSTAGE)                                                                       \
    {                                                                                                  \
        const int B_ = (S) % 3;                                                                        \
        const int W_ = ((S) + 2) % 3;                                                                  \
        bf16x8 a_[4];                                                                                  \
        /* ---- sub-phase 1: A frags + j=0 B frags || stage A0,A1,Br ; 12 MFMA ---- */                 \
        _Pragma("unroll")                                                                              \
        for (int i = 0; i < 4; ++i)                                                                    \
            a_[i] = *(const bf16x8*)&As[B_][(wm + i * 16 + r) * GBK + qs8];                            \
        bf16x8 br0 = *(const bf16x8*)&Brs[B_][(wn + r) * GBK + qs8];                                   \
        bf16x8 bz0 = *(const bf16x8*)&Bzs[B_][(wn + r) * GBK + qs8];                                   \
        bf16x8 bn0 = *(const bf16x8*)&Bns[B_][(wn + r) * GBK + qs8];                                   \
        if (DOSTAGE) {                                                                                 \
            glds16(AH + aOff0 + ((S) + 2) * GBK, &As[W_][tid * 8]);                                    \
            glds16(AH + aOff1 + ((S) + 2) * GBK, &As[W_][(256 + tid) * 8]);                            \
            glds16(Brt + bOff + ((S) + 2) * GBK, &Brs[W_][tid * 8]);                                   \
        }                                                                                              \
        __builtin_amdgcn_s_barrier();                                                                  \
        asm volatile("s_waitcnt lgkmcnt(0)" ::: "memory");                                             \
        __builtin_amdgcn_sched_barrier(0);                                                             \
        __builtin_amdgcn_s_setprio(1);                                                                 \
        _Pragma("unroll")                                                                              \
        for (int i = 0; i < 4; ++i) {                                                                  \
            accR[i][0] = __builtin_amdgcn_mfma_f32_16x16x32_bf16(a_[i], br0, accR[i][0], 0, 0, 0);     \
            accZ[i][0] = __builtin_amdgcn_mfma_f32_16x16x32_bf16(a_[i], bz0, accZ[i][0], 0, 0, 0);     \
            ACCN[i][0] = __builtin_amdgcn_mfma_f32_16x16x32_bf16(a_[i], bn0, ACCN[i][0], 0, 0, 0);     \
        }                                                                                              \
        __builtin_amdgcn_s_setprio(0);                                                                 \
        __builtin_amdgcn_s_barrier();                                                                  \
        /* ---- sub-phase 2: j=1 B frags || stage Bz,Bn ; 12 MFMA ---- */                              \
        bf16x8 br1 = *(const bf16x8*)&Brs[B_][(wn + 16 + r) * GBK + qs8];                              \
        bf16x8 bz1 = *(const bf16x8*)&Bzs[B_][(wn + 16 + r) * GBK + qs8];                              \
        bf16x8 bn1 = *(const bf16x8*)&Bns[B_][(wn + 16 + r) * GBK + qs8];                              \
        if (DOSTAGE) {                                                                                 \
            glds16(Bzt + bOff + ((S) + 2) * GBK, &Bzs[W_][tid * 8]);                                   \
            glds16(Bnt + bOff + ((S) + 2) * GBK, &Bns[W_][tid * 8]);                                   \
        }                                                                                              \
        __builtin_amdgcn_s_barrier();                                                                  \
        asm volatile("s_waitcnt lgkmcnt(0)" ::: "memory");                                             \
        __builtin_amdgcn_sched_barrier(0);                                                             \
        __builtin_amdgcn_s_setprio(1);                                                                 \
        _Pragma("unroll")                                                                              \
        for (int i = 0; i < 4; ++i) {                                                                  \
            accR[i][1] = __builtin_amdgcn_mfma_f32_16x16x32_bf16(a_[i], br1, accR[i][1], 0, 0, 0);     \
            accZ[i][1] = __builtin_amdgcn_mfma_f32_16x16x32_bf16(a_[i], bz1, accZ[i][1], 0, 0, 0);     \
            ACCN[i][1] = __builtin_amdgcn_mfma_f32_16x16x32_bf16(a_[i], bn1, ACCN[i][1], 0, 0, 0);     \
        }                                                                                              \
        __builtin_amdgcn_s_setprio(0);                                                                 \
        /* no trailing barrier: next step's WAITBAR barrier closes the phase */                        \
    }

// steady-state step: wait(tile S; tiles S+1 in flight) -> two sub-phases (stage S+2 inside)
#define GFULL(S, ACCN)                   \
    {                                    \
        WAITBAR(5);                      \
        GSTEP8(S, ACCN, 1);              \
    }

    GSTAGE(0, 0);
    GSTAGE(1, 1);
    // K-steps 0..15: A = proposed half, n-gate -> accNI
    GFULL(0,  accNI) GFULL(1,  accNI) GFULL(2,  accNI) GFULL(3,  accNI)
    GFULL(4,  accNI) GFULL(5,  accNI) GFULL(6,  accNI) GFULL(7,  accNI)
    GFULL(8,  accNI) GFULL(9,  accNI) GFULL(10, accNI) GFULL(11, accNI)
    GFULL(12, accNI) GFULL(13, accNI) GFULL(14, accNI) GFULL(15, accNI)
    // K-steps 16..31: A = emb half, n-gate -> accNH
    GFULL(16, accNH) GFULL(17, accNH) GFULL(18, accNH) GFULL(19, accNH)
    GFULL(20, accNH) GFULL(21, accNH) GFULL(22, accNH) GFULL(23, accNH)
    GFULL(24, accNH) GFULL(25, accNH) GFULL(26, accNH) GFULL(27, accNH)
    GFULL(28, accNH) GFULL(29, accNH)
    { WAITBAR(5); GSTEP8(30, accNH, 0); }  // S = 30 (no stage)
    { WAITBAR(0); GSTEP8(31, accNH, 0); }  // S = 31 (no stage)
#undef GSTAGE
#undef GSTEP8
#undef GFULL

    #pragma unroll
    for (int j = 0; j < 2; ++j) {
        const int col = colBase + wn + j * 16 + r;
        const float vbir = bir[col], vbiz = biz[col], vbin = bin[col], vbhn = bhn[col];
        #pragma unroll
        for (int i = 0; i < 4; ++i) {
            #pragma unroll
            for (int reg = 0; reg < 4; ++reg) {
                const int row = rowBase + wm + i * 16 + q * 4 + reg;
                if (row >= N) continue;
                float rg = sigmoidf_(accR[i][j][reg] + vbir);
                float zg = sigmoidf_(accZ[i][j][reg] + vbiz);
                float ng = tanhf(accNI[i][j][reg] + vbin + rg * (accNH[i][j][reg] + vbhn));
                float h = emb_f32[(size_t)row * H + col];
                out[(size_t)row * H + col] = (1.0f - zg) * ng + zg * h;
            }
        }
    }
}

extern "C" void kernel_launch(void* const* d_in, const int* in_sizes, int n_in,
                              void* d_out, int out_size, void* d_ws, size_t ws_size,
                              hipStream_t stream) {
    const float* emb     = (const float*)d_in[0];
    const int*   src_idx = (const int*)d_in[1];
    const int*   dst_idx = (const int*)d_in[2];
    const int*   etype   = (const int*)d_in[3];
    const float* W_edge  = (const float*)d_in[6];
    const float* b_edge  = (const float*)d_in[7];
    const float* Wir = (const float*)d_in[8];
    const float* Wiz = (const float*)d_in[9];
    const float* Win = (const float*)d_in[10];
    const float* bir = (const float*)d_in[11];
    const float* biz = (const float*)d_in[12];
    const float* bin = (const float*)d_in[13];
    const float* Whr = (const float*)d_in[14];
    const float* Whz = (const float*)d_in[15];
    const float* Whn = (const float*)d_in[16];
    const float* bhn = (const float*)d_in[17];

    const int E = in_sizes[1];
    const int N = in_sizes[0] / H;
    const int NH = N * H;

    char* ws = (char*)d_ws;
    int*            proposed = (int*)ws;                         ws += (size_t)NH * 4;  // fixed-point
    unsigned short* AH       = (unsigned short*)ws;              ws += (size_t)NH * 2 * 2;  // [N][1024]
    unsigned short* Brt      = (unsigned short*)ws;              ws += 512 * 1024 * 2;
    unsigned short* Bzt      = (unsigned short*)ws;              ws += 512 * 1024 * 2;
    unsigned short* Bnt      = (unsigned short*)ws;              ws += 512 * 1024 * 2;
    unsigned short* WeT      = (unsigned short*)ws;              ws += 3072 * 512 * 2;
    int*            meta     = (int*)ws;                         ws += 32 * 4;
    int*            perm     = (int*)ws;
    const int maxRowTiles = (E + EBM - 1) / EBM + NT;

    hipMemsetAsync(proposed, 0, (size_t)NH * 4, stream);
    hipMemsetAsync(meta, 0, 32 * 4, stream);
    hipMemsetAsync(perm, 0xFF, (size_t)maxRowTiles * EBM * 4, stream);

    const int n4 = NH / 4;
    conv_to_ah<<<(n4 + 255) / 256, 256, 0, stream>>>(emb, AH, n4, 1);       // emb -> high half
    conv_gru_w_kernel<<<(512 * 1024 + 255) / 256, 256, 0, stream>>>(
        Wir, Wiz, Win, Whr, Whz, Whn, Brt, Bzt, Bnt);
    conv_edge_w_kernel<<<(3072 * 512 + 255) / 256, 256, 0, stream>>>(W_edge, WeT);

    hist_kernel<<<(E + 255) / 256, 256, 0, stream>>>(etype, E, meta);
    prefix_kernel<<<1, 64, 0, stream>>>(meta);
    scatter_perm_kernel<<<(E + 255) / 256, 256, 0, stream>>>(etype, E, meta, perm);

    dim3 egrid(H / EBN, maxRowTiles);
    edge_msg_mfma<<<egrid, 256, 0, stream>>>(AH, src_idx, dst_idx, b_edge, WeT,
                                             meta, perm, proposed);

    conv_i2ah<<<(n4 + 255) / 256, 256, 0, stream>>>(proposed, AH, n4);      // proposed -> low half

    dim3 ggrid(H / GBN, (N + GBM - 1) / GBM);
    gru_mfma<<<ggrid, 256, 0, stream>>>(AH, emb, Brt, Bzt, Bnt,
                                        bir, biz, bin, bhn, (float*)d_out, N);
}